// Round 13
// baseline (596.886 us; speedup 1.0000x reference)
//
#include <hip/hip_runtime.h>
#include <cstdint>
#include <cstddef>

// ---------------------------------------------------------------------------
// TGN transformer attention layer, MI355X (gfx950).
//   k_prep  : pack k_q weights to f16; bq_eff (time-ones folded)
//   k_wcomp : Weff = [Wk;Wv] @ Wkv (f32) -> f16 fragment-packed; beff
//   CSR     : hist/scan/scatter over dst (scatter also emits dstc[pos])
//   k_q     : D rows: Q_ori -> Qh(f32), Kh_self, Vh_self (f16)
//   k_kv    : CSR-ordered GEMM + FULL fused attention epilogue:
//             Kh->LDS -> ee=exp(leaky(Q.K)) -> LDS; Vh->LDS; then per-column
//             segment reduction over the tile's contiguous dst runs with one
//             atomicAdd per (segment, column) into agg[D][264]
//             (cols 0..255 = sum ee*V, cols 256..263 = den per head).
//             No Kh/Vh/att ever hit global memory.
//   k_fin   : per-dst wave: + self-loop term, divide, relu, LayerNorm -> out
// ---------------------------------------------------------------------------

typedef _Float16 f16_t;
typedef _Float16 f16x8 __attribute__((ext_vector_type(8)));
typedef _Float16 f16x4 __attribute__((ext_vector_type(4)));
typedef float    f32x4 __attribute__((ext_vector_type(4)));

#define MFMA16(a, b, c) __builtin_amdgcn_mfma_f32_16x16x32_f16(a, b, c, 0, 0, 0)

#define BARRIER()                                         \
  do {                                                    \
    asm volatile("s_waitcnt lgkmcnt(0)" ::: "memory");    \
    __builtin_amdgcn_sched_barrier(0);                    \
    __builtin_amdgcn_s_barrier();                         \
    __builtin_amdgcn_sched_barrier(0);                    \
  } while (0)

static __device__ __forceinline__ f32x4 zero4() {
  f32x4 v; v[0] = 0.f; v[1] = 0.f; v[2] = 0.f; v[3] = 0.f; return v;
}

// w_j = 10^(-9 j / 99)  ->  exp2(j * (-9*log2(10)/99))
#define TIMEW_LOG2 (-0.30199346317157837f)

// ---------------------------------------------------------------------------
__global__ void k_prep(const float* __restrict__ wq_lin,
                       const float* __restrict__ bq_lin,
                       const float* __restrict__ wq,
                       const float* __restrict__ wk,
                       const float* __restrict__ wv,
                       f16_t* __restrict__ wq1,
                       f16_t* __restrict__ w3,
                       float* __restrict__ bqe) {
  int i = blockIdx.x * 256 + threadIdx.x;
  if (i < 32768) {
    int o = i >> 7, k = i & 127;
    wq1[i] = (f16_t)wq_lin[o * 228 + k];
  } else if (i < 229376) {
    int j = i - 32768;
    int r = j >> 8, k = j & 255;
    const float* src = (r < 256) ? wq : ((r < 512) ? wk : wv);
    w3[j] = (f16_t)src[(r & 255) * 256 + k];
  } else if (i < 229632) {
    int o = i - 229376;
    float s = bq_lin[o];
    for (int j = 0; j < 100; ++j) s += wq_lin[o * 228 + 128 + j];
    bqe[o] = s;
  }
}

// ---------------------------------------------------------------------------
// k_wcomp: Weff[oc][c] = sum_m W23[oc][m] * Wkv[m][c]; packed:
//   idx = kc*16384 + g*4096 + oc*8 + j   (c = kc*32 + g*8 + j)
// ---------------------------------------------------------------------------
__global__ __launch_bounds__(384) void k_wcomp(
    const float* __restrict__ wkv_lin, const float* __restrict__ bkv,
    const float* __restrict__ wk, const float* __restrict__ bk,
    const float* __restrict__ wv, const float* __restrict__ bv,
    f16_t* __restrict__ weffp, float* __restrict__ beff) {
  __shared__ float wrow[256];
  const int oc = blockIdx.x;
  const float* src = (oc < 256) ? (wk + (size_t)oc * 256)
                                : (wv + (size_t)(oc - 256) * 256);
  const int t = threadIdx.x;
  if (t < 256) wrow[t] = src[t];
  __syncthreads();

  float acc = 0.f;
  if (t < 356) {
#pragma unroll 4
    for (int m = 0; m < 256; ++m) acc += wrow[m] * wkv_lin[(size_t)m * 356 + t];
  }
  int kc = t >> 5, g = (t >> 3) & 3, j = t & 7;
  weffp[(size_t)kc * 16384 + g * 4096 + oc * 8 + j] = (f16_t)acc;

  if (t == 0) {
    float b = (oc < 256) ? bk[oc] : bv[oc - 256];
    for (int m = 0; m < 256; ++m) b += wrow[m] * bkv[m];
    beff[oc] = b;
  }
}

// ---------------------------------------------------------------------------
// CSR build
// ---------------------------------------------------------------------------
__global__ void k_hist(const int* __restrict__ dst, int* __restrict__ rs, int E) {
  int e = blockIdx.x * 256 + threadIdx.x;
  if (e < E) atomicAdd(&rs[dst[e] + 1], 1);
}

__global__ void k_scan(int* __restrict__ rs, int* __restrict__ cur, int D) {
  __shared__ int sd[1024];
  __shared__ int srun;
  const int t = threadIdx.x;
  if (t == 0) srun = 0;
  __syncthreads();
  for (int base = 0; base < D; base += 1024) {
    const int i = base + t;
    int c = (i < D) ? rs[i + 1] : 0;
    sd[t] = c;
    __syncthreads();
    for (int off = 1; off < 1024; off <<= 1) {
      int v = (t >= off) ? sd[t - off] : 0;
      __syncthreads();
      sd[t] += v;
      __syncthreads();
    }
    const int incl = sd[t];
    const int run = srun;
    __syncthreads();
    if (i < D) {
      cur[i] = run + incl - c;
      rs[i + 1] = run + incl;
    }
    if (t == 1023) srun = run + sd[1023];
    __syncthreads();
  }
}

__global__ void k_scatter(const int* __restrict__ dst, int* __restrict__ cur,
                          int* __restrict__ csr, int* __restrict__ dstc, int E) {
  int e = blockIdx.x * 256 + threadIdx.x;
  if (e < E) {
    int d = dst[e];
    int pos = atomicAdd(&cur[d], 1);
    csr[pos] = e;
    dstc[pos] = d;
  }
}

__global__ void k_sentinel(float* __restrict__ o, int n) {
  int i = blockIdx.x * 256 + threadIdx.x;
  if (i < n) o[i] = 1e30f;
}

// ---------------------------------------------------------------------------
// k_q: 64 dst rows per block, 8 waves (small kernel, D=25k rows).
// ---------------------------------------------------------------------------
__global__ __launch_bounds__(512) void k_q(
    const float* __restrict__ h, const float* __restrict__ bqe,
    const float* __restrict__ bq, const float* __restrict__ bk,
    const float* __restrict__ bv, const f16_t* __restrict__ wq1,
    const f16_t* __restrict__ w3, float* __restrict__ qhd,
    f16_t* __restrict__ khs, f16_t* __restrict__ vhs, int D) {
  __shared__ f16_t sm[64 * 256];
  f16_t* xs = sm;
  f16_t* ks = sm;
  const int tid = threadIdx.x;
  const int dbase = blockIdx.x * 64;

  {
    const int r = tid >> 3, q = tid & 7;
    const int dd = min(dbase + r, D - 1);
    const int sw = r & 7;
    const float* p = h + (size_t)dd * 128 + q * 16;
#pragma unroll
    for (int u = 0; u < 2; ++u) {
      float4 v0 = *(const float4*)(p + u * 8);
      float4 v1 = *(const float4*)(p + u * 8 + 4);
      f16x8 w8;
      w8[0] = (f16_t)v0.x; w8[1] = (f16_t)v0.y; w8[2] = (f16_t)v0.z; w8[3] = (f16_t)v0.w;
      w8[4] = (f16_t)v1.x; w8[5] = (f16_t)v1.y; w8[6] = (f16_t)v1.z; w8[7] = (f16_t)v1.w;
      *(f16x8*)&xs[r * 128 + (((2 * q + u) ^ sw) << 3)] = w8;
    }
  }
  __syncthreads();

  const int lane = tid & 63;
  const int wv_ = tid >> 6;
  const int m16 = lane & 15;
  const int g = lane >> 4;

  f32x4 acc1[4][2];
#pragma unroll
  for (int mt = 0; mt < 4; ++mt)
#pragma unroll
    for (int nt = 0; nt < 2; ++nt) acc1[mt][nt] = zero4();

#pragma unroll
  for (int kt = 0; kt < 4; ++kt) {
    f16x8 a[4];
#pragma unroll
    for (int mt = 0; mt < 4; ++mt) {
      int row = mt * 16 + m16;
      a[mt] = *(const f16x8*)&xs[row * 128 + ((((kt << 2) + g) ^ (row & 7)) << 3)];
    }
#pragma unroll
    for (int nt = 0; nt < 2; ++nt) {
      int col = wv_ * 32 + nt * 16 + m16;
      f16x8 b = *(const f16x8*)&wq1[(size_t)col * 128 + (kt << 5) + (g << 3)];
#pragma unroll
      for (int mt = 0; mt < 4; ++mt) acc1[mt][nt] = MFMA16(a[mt], b, acc1[mt][nt]);
    }
  }
  __syncthreads();

#pragma unroll
  for (int nt = 0; nt < 2; ++nt) {
    int col = wv_ * 32 + nt * 16 + m16;
    float bias = bqe[col];
#pragma unroll
    for (int mt = 0; mt < 4; ++mt)
#pragma unroll
      for (int j = 0; j < 4; ++j) {
        int row = mt * 16 + (g << 2) + j;
        ks[row * 256 + ((((col >> 3) ^ (row & 7)) << 3)) + (col & 7)] =
            (f16_t)(acc1[mt][nt][j] + bias);
      }
  }
  __syncthreads();

#pragma unroll
  for (int p = 0; p < 3; ++p) {
    const f16_t* wsec = w3 + ((size_t)p << 16);
    const float* bsec = (p == 0) ? bq : ((p == 1) ? bk : bv);
    f32x4 acc[4][2];
#pragma unroll
    for (int mt = 0; mt < 4; ++mt)
#pragma unroll
      for (int nt = 0; nt < 2; ++nt) acc[mt][nt] = zero4();
#pragma unroll
    for (int kt = 0; kt < 8; ++kt) {
      f16x8 a[4];
#pragma unroll
      for (int mt = 0; mt < 4; ++mt) {
        int row = mt * 16 + m16;
        a[mt] = *(const f16x8*)&ks[row * 256 + ((((kt << 2) + g) ^ (row & 7)) << 3)];
      }
#pragma unroll
      for (int nt = 0; nt < 2; ++nt) {
        int col = wv_ * 32 + nt * 16 + m16;
        f16x8 b = *(const f16x8*)&wsec[(size_t)col * 256 + (kt << 5) + (g << 3)];
#pragma unroll
        for (int mt = 0; mt < 4; ++mt) acc[mt][nt] = MFMA16(a[mt], b, acc[mt][nt]);
      }
    }
#pragma unroll
    for (int nt = 0; nt < 2; ++nt) {
      int col = wv_ * 32 + nt * 16 + m16;
      float bias = bsec[col];
#pragma unroll
      for (int mt = 0; mt < 4; ++mt)
#pragma unroll
        for (int j = 0; j < 4; ++j) {
          int row = mt * 16 + (g << 2) + j;
          int dd = dbase + row;
          if (dd < D) {
            float val = acc[mt][nt][j] + bias;
            if (p == 0)
              qhd[(size_t)dd * 256 + col] = val;
            else if (p == 1)
              khs[(size_t)dd * 256 + col] = (f16_t)val;
            else
              vhs[(size_t)dd * 256 + col] = (f16_t)val;
          }
        }
    }
  }
}

// ---------------------------------------------------------------------------
// k_kv: CSR-ordered GEMM + fully fused attention epilogue, 64-row tiles.
//   512 threads = 8 waves (wn 0..7, wave-tile 64x64, acc 4x4), 2 blocks/CU.
//   LDS: 2 x 20 KB A super-buffers; epilogue {ep[64][264] f16, ee[64][8] f32,
//   dst_s[64]} aliases them (36.1 KB).
// ---------------------------------------------------------------------------
__global__ __launch_bounds__(512, 4) void k_kv(
    const float* __restrict__ h, const float* __restrict__ f,
    const float* __restrict__ dt, const f16_t* __restrict__ weffp,
    const float* __restrict__ beff, const int* __restrict__ csr,
    const int* __restrict__ dstc, const float* __restrict__ qhd,
    float* __restrict__ agg, int D, int E) {
  __shared__ __align__(16) unsigned char smem[40960];  // 2 x 20 KB A supers

  const int tid = threadIdx.x;
  const int pbase = blockIdx.x * 64;
  const int row = tid >> 3, q = tid & 7;     // 64 rows x 8 col-octets
  const int lane = tid & 63, wn = tid >> 6;  // 8 waves = 8 col groups
  const int m16 = lane & 15, g = lane >> 4;

  const int pclamp = min(pbase + row, E - 1);
  const int ec = csr[pclamp];
  const float dtv = dt[ec];
  const float* hrow = h + (size_t)(D + ec) * 128 + q * 4;
  const float* frow = f + (size_t)ec * 128 + q * 4;

  auto stageA = [&](int buf, int sub, float4 v) {
    f16x4 w;
    w[0] = (f16_t)v.x; w[1] = (f16_t)v.y; w[2] = (f16_t)v.z; w[3] = (f16_t)v.w;
    *(f16x4*)(smem + buf * 20480 + sub * 5120 + row * 80 + q * 8) = w;
  };
  const f16_t* wb = weffp + (size_t)g * 4096 + ((size_t)(wn * 64 + m16) << 3);
  auto gldB = [&](int kc, f16x8* d) {
    const f16_t* pB = wb + (size_t)kc * 16384;
#pragma unroll
    for (int n = 0; n < 4; ++n) d[n] = *(const f16x8*)(pB + n * 128);
  };

  f32x4 acc[4][4];
#pragma unroll
  for (int mt = 0; mt < 4; ++mt)
#pragma unroll
    for (int n = 0; n < 4; ++n) acc[mt][n] = zero4();

  auto doChunk = [&](int kc, const f16x8* bbuf) {
    const unsigned char* Ac =
        smem + (((kc >> 2) == 1) ? 20480 : 0) + (kc & 3) * 5120;
#pragma unroll
    for (int mt = 0; mt < 4; ++mt) {
      f16x8 afr = *(const f16x8*)(Ac + (mt * 16 + m16) * 80 + g * 16);
#pragma unroll
      for (int n = 0; n < 4; ++n) acc[mt][n] = MFMA16(afr, bbuf[n], acc[mt][n]);
    }
  };

  // load h-super + f-super (gathered 512B rows); stage h->buf0, f->buf1
  float4 hv[4], fv[4];
#pragma unroll
  for (int s = 0; s < 4; ++s) hv[s] = *(const float4*)(hrow + s * 32);
#pragma unroll
  for (int s = 0; s < 4; ++s) fv[s] = *(const float4*)(frow + s * 32);
#pragma unroll
  for (int s = 0; s < 4; ++s) stageA(0, s, hv[s]);
#pragma unroll
  for (int s = 0; s < 4; ++s) stageA(1, s, fv[s]);
  BARRIER();  // A: h (buf0) + f (buf1) staged

  f16x8 bb0[4], bb1[4];
  gldB(0, bb0);
  gldB(1, bb1); doChunk(0, bb0);
  gldB(2, bb0); doChunk(1, bb1);
  gldB(3, bb1); doChunk(2, bb0);
  gldB(4, bb0); doChunk(3, bb1);
  BARRIER();  // B: buf0 (h) consumed, free

  // stage time-super into buf0 (consumed after barrier C)
#pragma unroll
  for (int s = 0; s < 4; ++s) {
    float4 a;
#pragma unroll
    for (int j = 0; j < 4; ++j) {
      int cc = s * 32 + q * 4 + j;
      ((float*)&a)[j] =
          (cc < 100) ? __cosf(dtv * exp2f(TIMEW_LOG2 * (float)cc)) : 0.f;
    }
    stageA(0, s, a);
  }
  gldB(5, bb1); doChunk(4, bb0);
  gldB(6, bb0); doChunk(5, bb1);
  gldB(7, bb1); doChunk(6, bb0);
  gldB(8, bb0); doChunk(7, bb1);
  BARRIER();  // C: buf0 (time) ready

  gldB(9, bb1);  doChunk(8, bb0);
  gldB(10, bb0); doChunk(9, bb1);
  gldB(11, bb1); doChunk(10, bb0);
  doChunk(11, bb1);
  BARRIER();  // D: K done, both bufs dead

  // ---- fused epilogue LDS layout (aliases A buffers):
  f16_t* ep    = (f16_t*)smem;               // [64][264] f16 = 33792 B
  float* ee_s  = (float*)(smem + 33792);     // [64][8] f32   =  2048 B
  int*   dst_s = (int*)(smem + 35840);       // [64]          =   256 B

  // pass 0: Kh (cols 0..255) -> LDS (waves 0..3)
  if (wn < 4) {
#pragma unroll
    for (int n = 0; n < 4; ++n) {
      const int c256 = wn * 64 + n * 16 + m16;
      const float bias = beff[c256];
#pragma unroll
      for (int mt = 0; mt < 4; ++mt)
#pragma unroll
        for (int j = 0; j < 4; ++j) {
          const int r2 = mt * 16 + (g << 2) + j;
          ep[r2 * 264 + c256] = (f16_t)(acc[mt][n][j] + bias);
        }
    }
  }
  BARRIER();  // E

  // ee = exp(leaky(Q[dst] . Kh)) -> LDS; also stage dst ids
  {
    const int r2 = tid >> 3, hp = tid & 7;
    const int p2 = pbase + r2;
    float eev = 0.f;
    if (p2 < E) {
      const int de = dstc[p2];
      const float* qp = qhd + (size_t)de * 256 + hp * 32;
      const f16_t* kp = ep + r2 * 264 + hp * 32;
      float s = 0.f;
#pragma unroll
      for (int jj = 0; jj < 32; jj += 4) {
        float4 qv = *(const float4*)(qp + jj);
        f16x4 kv = *(const f16x4*)(kp + jj);
        s += qv.x * (float)kv[0] + qv.y * (float)kv[1] +
             qv.z * (float)kv[2] + qv.w * (float)kv[3];
      }
      s = (s > 0.f) ? s : 0.2f * s;
      eev = __expf(s);
    }
    ee_s[r2 * 8 + hp] = eev;  // 0 for tail rows -> contributes nothing
    if (hp == 0) dst_s[r2] = dstc[min(p2, E - 1)];
  }
  BARRIER();  // F: Kh reads done before Vh staging overwrites ep

  // pass 1: Vh (channels 0..255) -> LDS cols 0..255 (waves 4..7)
  if (wn >= 4) {
#pragma unroll
    for (int n = 0; n < 4; ++n) {
      const int c256 = (wn - 4) * 64 + n * 16 + m16;
      const float bias = beff[256 + c256];
#pragma unroll
      for (int mt = 0; mt < 4; ++mt)
#pragma unroll
        for (int j = 0; j < 4; ++j) {
          const int r2 = mt * 16 + (g << 2) + j;
          ep[r2 * 264 + c256] = (f16_t)(acc[mt][n][j] + bias);
        }
    }
  }
  BARRIER();  // G

  // segment-reduce the tile: thread c accumulates over contiguous dst runs,
  // one atomicAdd per (segment, column).  cols 0..255 = ee*V; 256..263 = den.
  if (tid < 264) {
    const int c = tid;
    const int hd = (c < 256) ? (c >> 5) : (c - 256);
    float accv = 0.f;
    int cur_d = dst_s[0];
#pragma unroll 8
    for (int r = 0; r < 64; ++r) {
      int dd = dst_s[r];
      if (dd != cur_d) {
        atomicAdd(&agg[(size_t)cur_d * 264 + c], accv);
        accv = 0.f;
        cur_d = dd;
      }
      float eev = ee_s[r * 8 + hd];
      if (c < 256)
        accv = fmaf(eev, (float)ep[r * 264 + c], accv);
      else
        accv += eev;
    }
    atomicAdd(&agg[(size_t)cur_d * 264 + c], accv);
  }
}

// ---------------------------------------------------------------------------
// k_fin: one wave per dst node: agg + self-loop term, normalize, relu, LN.
// ---------------------------------------------------------------------------
__global__ __launch_bounds__(256) void k_fin(
    const float* __restrict__ qhd, const f16_t* __restrict__ khs,
    const f16_t* __restrict__ vhs, const float* __restrict__ agg,
    const float* __restrict__ lng, const float* __restrict__ lnb,
    float* __restrict__ out, int D) {
  const int lane = threadIdx.x & 63;
  const int d = blockIdx.x * 4 + (threadIdx.x >> 6);
  if (d >= D) return;
  const int c0 = lane * 4;
  const int hd = lane >> 3;

  float4 av = *(const float4*)(agg + (size_t)d * 264 + c0);
  float den = agg[(size_t)d * 264 + 256 + hd];

  // self-loop term (score from f32 Q and f16 K_self)
  {
    float4 qv = *(const float4*)(qhd + (size_t)d * 256 + c0);
    f16x4 ku = *(const f16x4*)(khs + (size_t)d * 256 + c0);
    f16x4 vu = *(const f16x4*)(vhs + (size_t)d * 256 + c0);
    float s = qv.x * (float)ku[0] + qv.y * (float)ku[1] +
              qv.z * (float)ku[2] + qv.w * (float)ku[3];
    s += __shfl_xor(s, 1); s += __shfl_xor(s, 2); s += __shfl_xor(s, 4);
    s = (s > 0.f) ? s : 0.2f * s;
    float ee = __expf(s);
    den += ee;
    av.x = fmaf(ee, (float)vu[0], av.x);
    av.y = fmaf(ee, (float)vu[1], av.y);
    av.z = fmaf(ee, (float)vu[2], av.z);
    av.w = fmaf(ee, (float)vu[3], av.w);
  }

  float x0 = fmaxf(av.x / den, 0.f), x1 = fmaxf(av.y / den, 0.f);
  float x2 = fmaxf(av.z / den, 0.f), x3 = fmaxf(av.w / den, 0.f);

  float s1 = x0 + x1 + x2 + x3;
#pragma unroll
  for (int m = 1; m < 64; m <<= 1) s1 += __shfl_xor(s1, m);
  float mu = s1 * (1.f / 256.f);
  float d0 = x0 - mu, d1 = x1 - mu, d2 = x2 - mu, d3 = x3 - mu;
  float s2 = d0 * d0 + d1 * d1 + d2 * d2 + d3 * d3;
#pragma unroll
  for (int m = 1; m < 64; m <<= 1) s2 += __shfl_xor(s2, m);
  float rstd = rsqrtf(s2 * (1.f / 256.f) + 1e-5f);

  float4 gg = *(const float4*)(lng + c0);
  float4 bb = *(const float4*)(lnb + c0);
  float4 o;
  o.x = d0 * rstd * gg.x + bb.x;
  o.y = d1 * rstd * gg.y + bb.y;
  o.z = d2 * rstd * gg.z + bb.z;
  o.w = d3 * rstd * gg.w + bb.w;
  *(float4*)(out + (size_t)d * 256 + c0) = o;
}

// ---------------------------------------------------------------------------
extern "C" void kernel_launch(void* const* d_in, const int* in_sizes, int n_in,
                              void* d_out, int out_size, void* d_ws,
                              size_t ws_size, hipStream_t stream) {
  const float* h       = (const float*)d_in[0];
  const float* f       = (const float*)d_in[1];
  const float* dt      = (const float*)d_in[2];
  const float* wq_lin  = (const float*)d_in[3];
  const float* bq_lin  = (const float*)d_in[4];
  const float* wkv_lin = (const float*)d_in[5];
  const float* bkv_lin = (const float*)d_in[6];
  const float* wq      = (const float*)d_in[7];
  const float* bq      = (const float*)d_in[8];
  const float* wk      = (const float*)d_in[9];
  const float* bk      = (const float*)d_in[10];
  const float* wv      = (const float*)d_in[11];
  const float* bv      = (const float*)d_in[12];
  const float* lng     = (const float*)d_in[13];
  const float* lnb     = (const float*)d_in[14];
  const int*   dst     = (const int*)d_in[15];

  const int S = in_sizes[0] / 128;
  const int E = in_sizes[2];
  const int D = S - E;
  float* out = (float*)d_out;

  char* p = (char*)d_ws;
  size_t off = 0;
  auto take = [&](size_t bytes) -> char* {
    char* r = p + off;
    off += (bytes + 255) & ~(size_t)255;
    return r;
  };
  f16_t* wq1   = (f16_t*)take((size_t)32768 * 2);
  f16_t* w3    = (f16_t*)take((size_t)196608 * 2);
  float* bqe   = (float*)take((size_t)256 * 4);
  f16_t* weffp = (f16_t*)take((size_t)196608 * 2);
  float* beff  = (float*)take((size_t)512 * 4);
  float* qhd   = (float*)take((size_t)D * 256 * 4);
  f16_t* khs   = (f16_t*)take((size_t)D * 256 * 2);
  f16_t* vhs   = (f16_t*)take((size_t)D * 256 * 2);
  float* agg   = (float*)take((size_t)D * 264 * 4);
  int*   rs    = (int*)  take((size_t)(D + 1) * 4);
  int*   cur   = (int*)  take((size_t)D * 4);
  int*   csr   = (int*)  take((size_t)E * 4);
  int*   dstc  = (int*)  take((size_t)E * 4);

  if (off > ws_size) {
    k_sentinel<<<(out_size + 255) / 256, 256, 0, stream>>>(out, out_size);
    return;
  }

  hipMemsetAsync(rs, 0, (size_t)(D + 1) * 4, stream);
  hipMemsetAsync(agg, 0, (size_t)D * 264 * 4, stream);
  k_prep<<<898, 256, 0, stream>>>(wq_lin, bq_lin, wq, wk, wv, wq1, w3, bqe);
  k_wcomp<<<512, 384, 0, stream>>>(wkv_lin, bkv_lin, wk, bk, wv, bv, weffp,
                                   beff);
  k_hist<<<(E + 255) / 256, 256, 0, stream>>>(dst, rs, E);
  k_scan<<<1, 1024, 0, stream>>>(rs, cur, D);
  k_scatter<<<(E + 255) / 256, 256, 0, stream>>>(dst, cur, csr, dstc, E);
  k_q<<<(D + 63) / 64, 512, 0, stream>>>(h, bqe, bq, bk, bv, wq1, w3, qhd, khs,
                                         vhs, D);
  k_kv<<<(E + 63) / 64, 512, 0, stream>>>(h, f, dt, weffp, beff, csr, dstc,
                                          qhd, agg, D, E);
  k_fin<<<(D + 3) / 4, 256, 0, stream>>>(qhd, khs, vhs, agg, lng, lnb, out, D);
}

// Round 14
// 503.703 us; speedup vs baseline: 1.1850x; 1.1850x over previous
//
#include <hip/hip_runtime.h>
#include <cstdint>
#include <cstddef>

// ---------------------------------------------------------------------------
// TGN transformer attention layer, MI355X (gfx950).
//   k_ph    : FUSED pack-weights (f16) + bq_eff + dst histogram
//   k_wcomp : Weff = [Wk;Wv] @ Wkv (f32) -> f16 fragment-packed; beff
//   k_scan  : wave-shfl scan over rs (4 barriers/1024-chunk)
//   k_sq    : FUSED csr scatter + k_q (Qh f32, Kh_self/Vh_self f16)
//   k_kv    : CSR-ordered GEMM + fused attention epilogue: Kh->LDS -> ee,
//             Vh->LDS -> split-half per-column segment reduce, one
//             atomicAdd per (segment,col) into agg[D][264].
//   k_fin   : per-dst wave: + self-loop, divide, relu, LayerNorm -> out
// ---------------------------------------------------------------------------

typedef _Float16 f16_t;
typedef _Float16 f16x8 __attribute__((ext_vector_type(8)));
typedef _Float16 f16x4 __attribute__((ext_vector_type(4)));
typedef float    f32x4 __attribute__((ext_vector_type(4)));

#define MFMA16(a, b, c) __builtin_amdgcn_mfma_f32_16x16x32_f16(a, b, c, 0, 0, 0)

#define BARRIER()                                         \
  do {                                                    \
    asm volatile("s_waitcnt lgkmcnt(0)" ::: "memory");    \
    __builtin_amdgcn_sched_barrier(0);                    \
    __builtin_amdgcn_s_barrier();                         \
    __builtin_amdgcn_sched_barrier(0);                    \
  } while (0)

static __device__ __forceinline__ f32x4 zero4() {
  f32x4 v; v[0] = 0.f; v[1] = 0.f; v[2] = 0.f; v[3] = 0.f; return v;
}

// w_j = 10^(-9 j / 99)  ->  exp2(j * (-9*log2(10)/99))
#define TIMEW_LOG2 (-0.30199346317157837f)

// ---------------------------------------------------------------------------
// k_ph: blocks [0,898) = weight pack; blocks [898,...) = dst histogram.
// ---------------------------------------------------------------------------
__global__ void k_ph(const float* __restrict__ wq_lin,
                     const float* __restrict__ bq_lin,
                     const float* __restrict__ wq,
                     const float* __restrict__ wk,
                     const float* __restrict__ wv,
                     const int* __restrict__ dst,
                     f16_t* __restrict__ wq1,
                     f16_t* __restrict__ w3,
                     float* __restrict__ bqe,
                     int* __restrict__ rs, int E) {
  const int b = blockIdx.x;
  if (b >= 898) {
    int e = (b - 898) * 256 + threadIdx.x;
    if (e < E) atomicAdd(&rs[dst[e] + 1], 1);
    return;
  }
  int i = b * 256 + threadIdx.x;
  if (i < 32768) {
    int o = i >> 7, k = i & 127;
    wq1[i] = (f16_t)wq_lin[o * 228 + k];
  } else if (i < 229376) {
    int j = i - 32768;
    int r = j >> 8, k = j & 255;
    const float* src = (r < 256) ? wq : ((r < 512) ? wk : wv);
    w3[j] = (f16_t)src[(r & 255) * 256 + k];
  } else if (i < 229632) {
    int o = i - 229376;
    float s = bq_lin[o];
    for (int j = 0; j < 100; ++j) s += wq_lin[o * 228 + 128 + j];
    bqe[o] = s;
  }
}

// ---------------------------------------------------------------------------
// k_wcomp: Weff[oc][c] = sum_m W23[oc][m] * Wkv[m][c]; packed:
//   idx = kc*16384 + g*4096 + oc*8 + j   (c = kc*32 + g*8 + j)
// ---------------------------------------------------------------------------
__global__ __launch_bounds__(384) void k_wcomp(
    const float* __restrict__ wkv_lin, const float* __restrict__ bkv,
    const float* __restrict__ wk, const float* __restrict__ bk,
    const float* __restrict__ wv, const float* __restrict__ bv,
    f16_t* __restrict__ weffp, float* __restrict__ beff) {
  __shared__ float wrow[256];
  const int oc = blockIdx.x;
  const float* src = (oc < 256) ? (wk + (size_t)oc * 256)
                                : (wv + (size_t)(oc - 256) * 256);
  const int t = threadIdx.x;
  if (t < 256) wrow[t] = src[t];
  __syncthreads();

  float acc = 0.f;
  if (t < 356) {
#pragma unroll 4
    for (int m = 0; m < 256; ++m) acc += wrow[m] * wkv_lin[(size_t)m * 356 + t];
  }
  int kc = t >> 5, g = (t >> 3) & 3, j = t & 7;
  weffp[(size_t)kc * 16384 + g * 4096 + oc * 8 + j] = (f16_t)acc;

  if (t == 0) {
    float b = (oc < 256) ? bk[oc] : bv[oc - 256];
    for (int m = 0; m < 256; ++m) b += wrow[m] * bkv[m];
    beff[oc] = b;
  }
}

// ---------------------------------------------------------------------------
// k_scan: single block, 1024 threads, wave-shfl inclusive scan.
// ---------------------------------------------------------------------------
__global__ __launch_bounds__(1024) void k_scan(int* __restrict__ rs,
                                               int* __restrict__ cur, int D) {
  __shared__ int wsum[16];
  __shared__ int srun;
  const int t = threadIdx.x, lane = t & 63, wv = t >> 6;
  if (t == 0) srun = 0;
  __syncthreads();
  for (int base = 0; base < D; base += 1024) {
    const int i = base + t;
    const int c = (i < D) ? rs[i + 1] : 0;
    int x = c;
#pragma unroll
    for (int off = 1; off < 64; off <<= 1) {
      int y = __shfl_up(x, off);
      if (lane >= off) x += y;
    }
    if (lane == 63) wsum[wv] = x;
    __syncthreads();
    if (wv == 0 && lane < 16) {
      int w = wsum[lane];
#pragma unroll
      for (int off = 1; off < 16; off <<= 1) {
        int y = __shfl_up(w, off);
        if (lane >= off) w += y;
      }
      wsum[lane] = w;
    }
    __syncthreads();
    const int incl = x + ((wv > 0) ? wsum[wv - 1] : 0);
    const int run = srun;
    __syncthreads();  // everyone has read srun
    if (i < D) {
      cur[i] = run + incl - c;
      rs[i + 1] = run + incl;
    }
    if (t == 1023) srun = run + incl;  // t=1023 holds chunk total
    __syncthreads();
  }
}

__global__ void k_sentinel(float* __restrict__ o, int n) {
  int i = blockIdx.x * 256 + threadIdx.x;
  if (i < n) o[i] = 1e30f;
}

// ---------------------------------------------------------------------------
// k_sq: blocks [0,nq) = k_q (64 dst rows, 8 waves); blocks [nq,..) = scatter.
// ---------------------------------------------------------------------------
__global__ __launch_bounds__(512) void k_sq(
    const float* __restrict__ h, const float* __restrict__ bqe,
    const float* __restrict__ bq, const float* __restrict__ bk,
    const float* __restrict__ bv, const f16_t* __restrict__ wq1,
    const f16_t* __restrict__ w3, float* __restrict__ qhd,
    f16_t* __restrict__ khs, f16_t* __restrict__ vhs, int D,
    const int* __restrict__ dst, int* __restrict__ cur,
    int* __restrict__ csr, int* __restrict__ dstc, int E, int nq) {
  __shared__ f16_t sm[64 * 256];
  if ((int)blockIdx.x >= nq) {
    int e = ((int)blockIdx.x - nq) * 512 + (int)threadIdx.x;
    if (e < E) {
      int d = dst[e];
      int pos = atomicAdd(&cur[d], 1);
      csr[pos] = e;
      dstc[pos] = d;
    }
    return;
  }
  f16_t* xs = sm;
  f16_t* ks = sm;
  const int tid = threadIdx.x;
  const int dbase = blockIdx.x * 64;

  {
    const int r = tid >> 3, q = tid & 7;
    const int dd = min(dbase + r, D - 1);
    const int sw = r & 7;
    const float* p = h + (size_t)dd * 128 + q * 16;
#pragma unroll
    for (int u = 0; u < 2; ++u) {
      float4 v0 = *(const float4*)(p + u * 8);
      float4 v1 = *(const float4*)(p + u * 8 + 4);
      f16x8 w8;
      w8[0] = (f16_t)v0.x; w8[1] = (f16_t)v0.y; w8[2] = (f16_t)v0.z; w8[3] = (f16_t)v0.w;
      w8[4] = (f16_t)v1.x; w8[5] = (f16_t)v1.y; w8[6] = (f16_t)v1.z; w8[7] = (f16_t)v1.w;
      *(f16x8*)&xs[r * 128 + (((2 * q + u) ^ sw) << 3)] = w8;
    }
  }
  __syncthreads();

  const int lane = tid & 63;
  const int wv_ = tid >> 6;
  const int m16 = lane & 15;
  const int g = lane >> 4;

  f32x4 acc1[4][2];
#pragma unroll
  for (int mt = 0; mt < 4; ++mt)
#pragma unroll
    for (int nt = 0; nt < 2; ++nt) acc1[mt][nt] = zero4();

#pragma unroll
  for (int kt = 0; kt < 4; ++kt) {
    f16x8 a[4];
#pragma unroll
    for (int mt = 0; mt < 4; ++mt) {
      int row = mt * 16 + m16;
      a[mt] = *(const f16x8*)&xs[row * 128 + ((((kt << 2) + g) ^ (row & 7)) << 3)];
    }
#pragma unroll
    for (int nt = 0; nt < 2; ++nt) {
      int col = wv_ * 32 + nt * 16 + m16;
      f16x8 b = *(const f16x8*)&wq1[(size_t)col * 128 + (kt << 5) + (g << 3)];
#pragma unroll
      for (int mt = 0; mt < 4; ++mt) acc1[mt][nt] = MFMA16(a[mt], b, acc1[mt][nt]);
    }
  }
  __syncthreads();

#pragma unroll
  for (int nt = 0; nt < 2; ++nt) {
    int col = wv_ * 32 + nt * 16 + m16;
    float bias = bqe[col];
#pragma unroll
    for (int mt = 0; mt < 4; ++mt)
#pragma unroll
      for (int j = 0; j < 4; ++j) {
        int row = mt * 16 + (g << 2) + j;
        ks[row * 256 + ((((col >> 3) ^ (row & 7)) << 3)) + (col & 7)] =
            (f16_t)(acc1[mt][nt][j] + bias);
      }
  }
  __syncthreads();

#pragma unroll
  for (int p = 0; p < 3; ++p) {
    const f16_t* wsec = w3 + ((size_t)p << 16);
    const float* bsec = (p == 0) ? bq : ((p == 1) ? bk : bv);
    f32x4 acc[4][2];
#pragma unroll
    for (int mt = 0; mt < 4; ++mt)
#pragma unroll
      for (int nt = 0; nt < 2; ++nt) acc[mt][nt] = zero4();
#pragma unroll
    for (int kt = 0; kt < 8; ++kt) {
      f16x8 a[4];
#pragma unroll
      for (int mt = 0; mt < 4; ++mt) {
        int row = mt * 16 + m16;
        a[mt] = *(const f16x8*)&ks[row * 256 + ((((kt << 2) + g) ^ (row & 7)) << 3)];
      }
#pragma unroll
      for (int nt = 0; nt < 2; ++nt) {
        int col = wv_ * 32 + nt * 16 + m16;
        f16x8 b = *(const f16x8*)&wsec[(size_t)col * 256 + (kt << 5) + (g << 3)];
#pragma unroll
        for (int mt = 0; mt < 4; ++mt) acc[mt][nt] = MFMA16(a[mt], b, acc[mt][nt]);
      }
    }
#pragma unroll
    for (int nt = 0; nt < 2; ++nt) {
      int col = wv_ * 32 + nt * 16 + m16;
      float bias = bsec[col];
#pragma unroll
      for (int mt = 0; mt < 4; ++mt)
#pragma unroll
        for (int j = 0; j < 4; ++j) {
          int row = mt * 16 + (g << 2) + j;
          int dd = dbase + row;
          if (dd < D) {
            float val = acc[mt][nt][j] + bias;
            if (p == 0)
              qhd[(size_t)dd * 256 + col] = val;
            else if (p == 1)
              khs[(size_t)dd * 256 + col] = (f16_t)val;
            else
              vhs[(size_t)dd * 256 + col] = (f16_t)val;
          }
        }
    }
  }
}

// ---------------------------------------------------------------------------
// k_kv: CSR-ordered GEMM + fused attention epilogue, 64-row tiles.
//   512 threads = 8 waves (wn 0..7, wave-tile 64x64, acc 4x4), 2 blocks/CU.
//   Epilogue: split-half segment reduce (512 threads active).
// ---------------------------------------------------------------------------
__global__ __launch_bounds__(512, 4) void k_kv(
    const float* __restrict__ h, const float* __restrict__ f,
    const float* __restrict__ dt, const f16_t* __restrict__ weffp,
    const float* __restrict__ beff, const int* __restrict__ csr,
    const int* __restrict__ dstc, const float* __restrict__ qhd,
    float* __restrict__ agg, int D, int E) {
  __shared__ __align__(16) unsigned char smem[40960];  // 2 x 20 KB A supers

  const int tid = threadIdx.x;
  const int pbase = blockIdx.x * 64;
  const int row = tid >> 3, q = tid & 7;     // 64 rows x 8 col-octets
  const int lane = tid & 63, wn = tid >> 6;  // 8 waves = 8 col groups
  const int m16 = lane & 15, g = lane >> 4;

  const int pclamp = min(pbase + row, E - 1);
  const int ec = csr[pclamp];
  const float dtv = dt[ec];
  const float* hrow = h + (size_t)(D + ec) * 128 + q * 4;
  const float* frow = f + (size_t)ec * 128 + q * 4;

  auto stageA = [&](int buf, int sub, float4 v) {
    f16x4 w;
    w[0] = (f16_t)v.x; w[1] = (f16_t)v.y; w[2] = (f16_t)v.z; w[3] = (f16_t)v.w;
    *(f16x4*)(smem + buf * 20480 + sub * 5120 + row * 80 + q * 8) = w;
  };
  const f16_t* wb = weffp + (size_t)g * 4096 + ((size_t)(wn * 64 + m16) << 3);
  auto gldB = [&](int kc, f16x8* d) {
    const f16_t* pB = wb + (size_t)kc * 16384;
#pragma unroll
    for (int n = 0; n < 4; ++n) d[n] = *(const f16x8*)(pB + n * 128);
  };

  f32x4 acc[4][4];
#pragma unroll
  for (int mt = 0; mt < 4; ++mt)
#pragma unroll
    for (int n = 0; n < 4; ++n) acc[mt][n] = zero4();

  auto doChunk = [&](int kc, const f16x8* bbuf) {
    const unsigned char* Ac =
        smem + (((kc >> 2) == 1) ? 20480 : 0) + (kc & 3) * 5120;
#pragma unroll
    for (int mt = 0; mt < 4; ++mt) {
      f16x8 afr = *(const f16x8*)(Ac + (mt * 16 + m16) * 80 + g * 16);
#pragma unroll
      for (int n = 0; n < 4; ++n) acc[mt][n] = MFMA16(afr, bbuf[n], acc[mt][n]);
    }
  };

  // load h-super + f-super (gathered 512B rows); issue B(0),B(1) early so
  // their L2 latency hides under the gather + staging + barrier
  float4 hv[4], fv[4];
#pragma unroll
  for (int s = 0; s < 4; ++s) hv[s] = *(const float4*)(hrow + s * 32);
#pragma unroll
  for (int s = 0; s < 4; ++s) fv[s] = *(const float4*)(frow + s * 32);
  f16x8 bb0[4], bb1[4];
  gldB(0, bb0);
  gldB(1, bb1);
#pragma unroll
  for (int s = 0; s < 4; ++s) stageA(0, s, hv[s]);
#pragma unroll
  for (int s = 0; s < 4; ++s) stageA(1, s, fv[s]);
  BARRIER();  // A: h (buf0) + f (buf1) staged

  doChunk(0, bb0); gldB(2, bb0);
  doChunk(1, bb1); gldB(3, bb1);
  doChunk(2, bb0); gldB(4, bb0);
  doChunk(3, bb1);
  BARRIER();  // B: buf0 (h) consumed, free

  // stage time-super into buf0 (consumed after barrier C)
#pragma unroll
  for (int s = 0; s < 4; ++s) {
    float4 a;
#pragma unroll
    for (int j = 0; j < 4; ++j) {
      int cc = s * 32 + q * 4 + j;
      ((float*)&a)[j] =
          (cc < 100) ? __cosf(dtv * exp2f(TIMEW_LOG2 * (float)cc)) : 0.f;
    }
    stageA(0, s, a);
  }
  gldB(5, bb1); doChunk(4, bb0);
  gldB(6, bb0); doChunk(5, bb1);
  gldB(7, bb1); doChunk(6, bb0);
  gldB(8, bb0); doChunk(7, bb1);
  BARRIER();  // C: buf0 (time) ready

  gldB(9, bb1);  doChunk(8, bb0);
  gldB(10, bb0); doChunk(9, bb1);
  gldB(11, bb1); doChunk(10, bb0);
  doChunk(11, bb1);
  BARRIER();  // D: K done, both bufs dead

  // ---- fused epilogue LDS layout (aliases A buffers):
  f16_t* ep    = (f16_t*)smem;               // [64][264] f16 = 33792 B
  float* ee_s  = (float*)(smem + 33792);     // [64][8] f32   =  2048 B
  int*   dst_s = (int*)(smem + 35840);       // [64]          =   256 B

  // pass 0: Kh (cols 0..255) -> LDS (waves 0..3)
  if (wn < 4) {
#pragma unroll
    for (int n = 0; n < 4; ++n) {
      const int c256 = wn * 64 + n * 16 + m16;
      const float bias = beff[c256];
#pragma unroll
      for (int mt = 0; mt < 4; ++mt)
#pragma unroll
        for (int j = 0; j < 4; ++j) {
          const int r2 = mt * 16 + (g << 2) + j;
          ep[r2 * 264 + c256] = (f16_t)(acc[mt][n][j] + bias);
        }
    }
  }
  BARRIER();  // E

  // ee = exp(leaky(Q[dst] . Kh)) -> LDS; also stage dst ids
  {
    const int r2 = tid >> 3, hp = tid & 7;
    const int p2 = pbase + r2;
    float eev = 0.f;
    if (p2 < E) {
      const int de = dstc[p2];
      const float* qp = qhd + (size_t)de * 256 + hp * 32;
      const f16_t* kp = ep + r2 * 264 + hp * 32;
      float s = 0.f;
#pragma unroll
      for (int jj = 0; jj < 32; jj += 4) {
        float4 qv = *(const float4*)(qp + jj);
        f16x4 kv = *(const f16x4*)(kp + jj);
        s += qv.x * (float)kv[0] + qv.y * (float)kv[1] +
             qv.z * (float)kv[2] + qv.w * (float)kv[3];
      }
      s = (s > 0.f) ? s : 0.2f * s;
      eev = __expf(s);
    }
    ee_s[r2 * 8 + hp] = eev;  // 0 for tail rows -> contributes nothing
    if (hp == 0) dst_s[r2] = dstc[min(p2, E - 1)];
  }
  BARRIER();  // F: Kh reads done before Vh staging overwrites ep

  // pass 1: Vh (channels 0..255) -> LDS cols 0..255 (waves 4..7)
  if (wn >= 4) {
#pragma unroll
    for (int n = 0; n < 4; ++n) {
      const int c256 = (wn - 4) * 64 + n * 16 + m16;
      const float bias = beff[256 + c256];
#pragma unroll
      for (int mt = 0; mt < 4; ++mt)
#pragma unroll
        for (int j = 0; j < 4; ++j) {
          const int r2 = mt * 16 + (g << 2) + j;
          ep[r2 * 264 + c256] = (f16_t)(acc[mt][n][j] + bias);
        }
    }
  }
  BARRIER();  // G

  // split-half segment reduce: half = tid>>8 covers 32 rows; V col = tid&255.
  {
    const int half = tid >> 8;
    const int c = tid & 255;
    const int hd = c >> 5;
    const int r0 = half * 32;
    float accv = 0.f;
    int cur_d = dst_s[r0];
#pragma unroll 8
    for (int r = r0; r < r0 + 32; ++r) {
      int dd = dst_s[r];
      if (dd != cur_d) {
        atomicAdd(&agg[(size_t)cur_d * 264 + c], accv);
        accv = 0.f;
        cur_d = dd;
      }
      accv = fmaf(ee_s[r * 8 + hd], (float)ep[r * 264 + c], accv);
    }
    atomicAdd(&agg[(size_t)cur_d * 264 + c], accv);
  }
  // den: 16 threads (half x 8 heads)
  if (tid < 16) {
    const int half = tid >> 3, hd = tid & 7;
    const int r0 = half * 32;
    float accv = 0.f;
    int cur_d = dst_s[r0];
#pragma unroll 8
    for (int r = r0; r < r0 + 32; ++r) {
      int dd = dst_s[r];
      if (dd != cur_d) {
        atomicAdd(&agg[(size_t)cur_d * 264 + 256 + hd], accv);
        accv = 0.f;
        cur_d = dd;
      }
      accv += ee_s[r * 8 + hd];
    }
    atomicAdd(&agg[(size_t)cur_d * 264 + 256 + hd], accv);
  }
}

// ---------------------------------------------------------------------------
// k_fin: one wave per dst node: agg + self-loop term, normalize, relu, LN.
// ---------------------------------------------------------------------------
__global__ __launch_bounds__(256) void k_fin(
    const float* __restrict__ qhd, const f16_t* __restrict__ khs,
    const f16_t* __restrict__ vhs, const float* __restrict__ agg,
    const float* __restrict__ lng, const float* __restrict__ lnb,
    float* __restrict__ out, int D) {
  const int lane = threadIdx.x & 63;
  const int d = blockIdx.x * 4 + (threadIdx.x >> 6);
  if (d >= D) return;
  const int c0 = lane * 4;
  const int hd = lane >> 3;

  float4 av = *(const float4*)(agg + (size_t)d * 264 + c0);
  float den = agg[(size_t)d * 264 + 256 + hd];

  // self-loop term (score from f32 Q and f16 K_self)
  {
    float4 qv = *(const float4*)(qhd + (size_t)d * 256 + c0);
    f16x4 ku = *(const f16x4*)(khs + (size_t)d * 256 + c0);
    f16x4 vu = *(const f16x4*)(vhs + (size_t)d * 256 + c0);
    float s = qv.x * (float)ku[0] + qv.y * (float)ku[1] +
              qv.z * (float)ku[2] + qv.w * (float)ku[3];
    s += __shfl_xor(s, 1); s += __shfl_xor(s, 2); s += __shfl_xor(s, 4);
    s = (s > 0.f) ? s : 0.2f * s;
    float ee = __expf(s);
    den += ee;
    av.x = fmaf(ee, (float)vu[0], av.x);
    av.y = fmaf(ee, (float)vu[1], av.y);
    av.z = fmaf(ee, (float)vu[2], av.z);
    av.w = fmaf(ee, (float)vu[3], av.w);
  }

  float x0 = fmaxf(av.x / den, 0.f), x1 = fmaxf(av.y / den, 0.f);
  float x2 = fmaxf(av.z / den, 0.f), x3 = fmaxf(av.w / den, 0.f);

  float s1 = x0 + x1 + x2 + x3;
#pragma unroll
  for (int m = 1; m < 64; m <<= 1) s1 += __shfl_xor(s1, m);
  float mu = s1 * (1.f / 256.f);
  float d0 = x0 - mu, d1 = x1 - mu, d2 = x2 - mu, d3 = x3 - mu;
  float s2 = d0 * d0 + d1 * d1 + d2 * d2 + d3 * d3;
#pragma unroll
  for (int m = 1; m < 64; m <<= 1) s2 += __shfl_xor(s2, m);
  float rstd = rsqrtf(s2 * (1.f / 256.f) + 1e-5f);

  float4 gg = *(const float4*)(lng + c0);
  float4 bb = *(const float4*)(lnb + c0);
  float4 o;
  o.x = d0 * rstd * gg.x + bb.x;
  o.y = d1 * rstd * gg.y + bb.y;
  o.z = d2 * rstd * gg.z + bb.z;
  o.w = d3 * rstd * gg.w + bb.w;
  *(float4*)(out + (size_t)d * 256 + c0) = o;
}

// ---------------------------------------------------------------------------
extern "C" void kernel_launch(void* const* d_in, const int* in_sizes, int n_in,
                              void* d_out, int out_size, void* d_ws,
                              size_t ws_size, hipStream_t stream) {
  const float* h       = (const float*)d_in[0];
  const float* f       = (const float*)d_in[1];
  const float* dt      = (const float*)d_in[2];
  const float* wq_lin  = (const float*)d_in[3];
  const float* bq_lin  = (const float*)d_in[4];
  const float* wkv_lin = (const float*)d_in[5];
  const float* bkv_lin = (const float*)d_in[6];
  const float* wq      = (const float*)d_in[7];
  const float* bq      = (const float*)d_in[8];
  const float* wk      = (const float*)d_in[9];
  const float* bk      = (const float*)d_in[10];
  const float* wv      = (const float*)d_in[11];
  const float* bv      = (const float*)d_in[12];
  const float* lng     = (const float*)d_in[13];
  const float* lnb     = (const float*)d_in[14];
  const int*   dst     = (const int*)d_in[15];

  const int S = in_sizes[0] / 128;
  const int E = in_sizes[2];
  const int D = S - E;
  float* out = (float*)d_out;

  char* p = (char*)d_ws;
  size_t off = 0;
  auto take = [&](size_t bytes) -> char* {
    char* r = p + off;
    off += (bytes + 255) & ~(size_t)255;
    return r;
  };
  f16_t* wq1   = (f16_t*)take((size_t)32768 * 2);
  f16_t* w3    = (f16_t*)take((size_t)196608 * 2);
  float* bqe   = (float*)take((size_t)256 * 4);
  f16_t* weffp = (f16_t*)take((size_t)196608 * 2);
  float* beff  = (float*)take((size_t)512 * 4);
  float* qhd   = (float*)take((size_t)D * 256 * 4);
  f16_t* khs   = (f16_t*)take((size_t)D * 256 * 2);
  f16_t* vhs   = (f16_t*)take((size_t)D * 256 * 2);
  float* agg   = (float*)take((size_t)D * 264 * 4);  // agg,rs adjacent:
  int*   rs    = (int*)  take((size_t)(D + 1) * 4);  // single memset below
  int*   cur   = (int*)  take((size_t)D * 4);
  int*   csr   = (int*)  take((size_t)E * 4);
  int*   dstc  = (int*)  take((size_t)E * 4);

  if (off > ws_size) {
    k_sentinel<<<(out_size + 255) / 256, 256, 0, stream>>>(out, out_size);
    return;
  }

  const int nq = (D + 63) / 64;
  const int nsc = (E + 511) / 512;

  // one memset covers agg..rs (take() keeps them contiguous incl. padding)
  hipMemsetAsync(agg, 0, (size_t)((char*)rs - (char*)agg) + (size_t)(D + 1) * 4,
                 stream);
  k_ph<<<898 + (E + 255) / 256, 256, 0, stream>>>(wq_lin, bq_lin, wq, wk, wv,
                                                  dst, wq1, w3, bqe, rs, E);
  k_wcomp<<<512, 384, 0, stream>>>(wkv_lin, bkv_lin, wk, bk, wv, bv, weffp,
                                   beff);
  k_scan<<<1, 1024, 0, stream>>>(rs, cur, D);
  k_sq<<<nq + nsc, 512, 0, stream>>>(h, bqe, bq, bk, bv, wq1, w3, qhd, khs,
                                     vhs, D, dst, cur, csr, dstc, E, nq);
  k_kv<<<(E + 63) / 64, 512, 0, stream>>>(h, f, dt, weffp, beff, csr, dstc,
                                          qhd, agg, D, E);
  k_fin<<<(D + 3) / 4, 256, 0, stream>>>(qhd, khs, vhs, agg, lng, lnb, out, D);
}